// Round 1
// baseline (1320.139 us; speedup 1.0000x reference)
//
#include <hip/hip_runtime.h>
#include <hip/hip_bf16.h>

#define B_ 128
#define D_ 10
#define L_ 1024
#define E_ 300
#define TWO_E 600
#define C_ 5
#define NODES (2 * L_ - 1)   // 2047

// ---------------------------------------------------------------------------
// Kernel 1: h0 = relu(embedding[word_ids])   one wave per row
// ---------------------------------------------------------------------------
template <typename HT>
__global__ __launch_bounds__(256) void gather_relu_k(
    const int* __restrict__ word_ids, const float* __restrict__ emb,
    HT* __restrict__ h0) {
  int wid = (blockIdx.x * blockDim.x + threadIdx.x) >> 6;
  int lane = threadIdx.x & 63;
  if (wid >= B_ * L_) return;
  int w = word_ids[wid];
  const float* src = emb + (size_t)w * E_;
  HT* dst = h0 + (size_t)wid * E_;
  for (int e = lane; e < E_; e += 64) {
    float v = src[e];
    v = v > 0.f ? v : 0.f;
    dst[e] = (HT)v;
  }
}

// ---------------------------------------------------------------------------
// Kernel 2: projection logits[row, c] = h[row,:] . P_w[c,:] + P_b[c]
// one wave per row; wave shuffle-reduce 5 accumulators
// ---------------------------------------------------------------------------
template <typename HT>
__global__ __launch_bounds__(256) void project_k(
    const HT* __restrict__ h, const float* __restrict__ Pw,
    const float* __restrict__ Pb, float* __restrict__ out,
    int n_per_b, int node_off) {
  int wid = (blockIdx.x * blockDim.x + threadIdx.x) >> 6;
  int lane = threadIdx.x & 63;
  int total = B_ * n_per_b;
  if (wid >= total) return;
  int b = wid / n_per_b;
  int n = wid % n_per_b;
  const HT* row = h + (size_t)wid * E_;
  float acc[C_] = {0.f, 0.f, 0.f, 0.f, 0.f};
  for (int e = lane; e < E_; e += 64) {
    float v = (float)row[e];
#pragma unroll
    for (int c = 0; c < C_; c++) acc[c] += v * Pw[c * E_ + e];
  }
#pragma unroll
  for (int c = 0; c < C_; c++) {
#pragma unroll
    for (int s = 32; s > 0; s >>= 1) acc[c] += __shfl_down(acc[c], s);
  }
  if (lane == 0) {
    float* o = out + ((size_t)b * NODES + node_off + n) * C_;
#pragma unroll
    for (int c = 0; c < C_; c++) o[c] = acc[c] + Pb[c];
  }
}

// ---------------------------------------------------------------------------
// Kernel 3: combine GEMM for one level.
//   A = h_in viewed as [M, 600] row-major (pair rows are contiguous)
//   Bmat = W_w [300, 600] row-major ; out[m,e] = sum_f A[m,f]*W_w[e,f]
//   h_out[m, e] = relu(out + W_b[e])
// BM=64, BN=64 (5 N-tiles cover 300), BK=8, 256 threads, 4x4 micro-tile.
// ---------------------------------------------------------------------------
template <typename HT>
__global__ __launch_bounds__(256) void combine_k(
    const HT* __restrict__ h_in, const float* __restrict__ Ww,
    const float* __restrict__ Wb, HT* __restrict__ h_out, int M) {
  const int BK = 8;
  __shared__ float As[BK][64];
  __shared__ float Bs[BK][64];
  int tid = threadIdx.x;
  int tx = tid & 15, ty = tid >> 4;
  int m0 = blockIdx.x * 64;
  int n0 = blockIdx.y * 64;

  float acc[4][4] = {};

  int lr = tid >> 2;         // 0..63  row within tile
  int lc = (tid & 3) * 2;    // 0,2,4,6  k-offset within tile

  for (int k0 = 0; k0 < TWO_E; k0 += BK) {
    // stage A: 64 rows x 8 k  (A[m,f] = h_in flat [m*600 + f])
    {
      size_t base = (size_t)(m0 + lr) * TWO_E + k0 + lc;
      float v0 = (float)h_in[base];
      float v1 = (float)h_in[base + 1];
      As[lc][lr] = v0;
      As[lc + 1][lr] = v1;
    }
    // stage B: 64 n-rows x 8 k from W_w[n, f], guard n < 300
    {
      int n = n0 + lr;
      float v0 = 0.f, v1 = 0.f;
      if (n < E_) {
        size_t base = (size_t)n * TWO_E + k0 + lc;
        v0 = Ww[base];
        v1 = Ww[base + 1];
      }
      Bs[lc][lr] = v0;
      Bs[lc + 1][lr] = v1;
    }
    __syncthreads();
#pragma unroll
    for (int k = 0; k < BK; k++) {
      float a[4], b[4];
#pragma unroll
      for (int i = 0; i < 4; i++) a[i] = As[k][ty * 4 + i];
#pragma unroll
      for (int j = 0; j < 4; j++) b[j] = Bs[k][tx * 4 + j];
#pragma unroll
      for (int i = 0; i < 4; i++)
#pragma unroll
        for (int j = 0; j < 4; j++) acc[i][j] += a[i] * b[j];
    }
    __syncthreads();
  }

#pragma unroll
  for (int i = 0; i < 4; i++) {
    int m = m0 + ty * 4 + i;
#pragma unroll
    for (int j = 0; j < 4; j++) {
      int n = n0 + tx * 4 + j;
      if (n < E_) {
        float v = acc[i][j] + Wb[n];
        v = v > 0.f ? v : 0.f;
        h_out[(size_t)m * E_ + n] = (HT)v;
      }
    }
  }
}

// ---------------------------------------------------------------------------
template <typename HT>
static void run_all(const int* wid, const float* emb, const float* Ww,
                    const float* Wb, const float* Pw, const float* Pb,
                    float* out, void* ws, hipStream_t stream) {
  HT* hA = (HT*)ws;
  HT* hB = hA + (size_t)B_ * L_ * E_;

  // leaves
  gather_relu_k<HT><<<(B_ * L_) / 4, 256, 0, stream>>>(wid, emb, hA);
  project_k<HT><<<(B_ * L_ + 3) / 4, 256, 0, stream>>>(hA, Pw, Pb, out, L_, 0);

  HT* cur = hA;
  int node_off = L_;
  for (int lev = 1; lev <= D_; lev++) {
    int n_half = L_ >> lev;
    int M = B_ * n_half;
    HT* nxt = (lev & 1) ? hB : hA;
    combine_k<HT><<<dim3(M / 64, 5), 256, 0, stream>>>(cur, Ww, Wb, nxt, M);
    project_k<HT><<<(M + 3) / 4, 256, 0, stream>>>(nxt, Pw, Pb, out, n_half,
                                                   node_off);
    node_off += n_half;
    cur = nxt;
  }
}

extern "C" void kernel_launch(void* const* d_in, const int* in_sizes, int n_in,
                              void* d_out, int out_size, void* d_ws,
                              size_t ws_size, hipStream_t stream) {
  const int* word_ids = (const int*)d_in[0];
  const float* emb = (const float*)d_in[1];
  const float* Ww = (const float*)d_in[2];
  const float* Wb = (const float*)d_in[3];
  const float* Pw = (const float*)d_in[4];
  const float* Pb = (const float*)d_in[5];
  float* out = (float*)d_out;

  size_t need_f32 = ((size_t)B_ * L_ * E_ + (size_t)B_ * (L_ / 2) * E_) * 4;
  if (ws_size >= need_f32) {
    run_all<float>(word_ids, emb, Ww, Wb, Pw, Pb, out, d_ws, stream);
  } else {
    run_all<__hip_bfloat16>(word_ids, emb, Ww, Wb, Pw, Pb, out, d_ws, stream);
  }
}

// Round 2
// 294.470 us; speedup vs baseline: 4.4831x; 4.4831x over previous
//
#include <hip/hip_runtime.h>
#include <hip/hip_bf16.h>

#define B_ 128
#define D_ 10
#define L_ 1024
#define E_ 300
#define C_ 5
#define NODES 2047
#define HSTR 304   // h row stride in elems (300 + 4 zero pad)
#define KP 608     // combine K (= 2*HSTR), 19 * 32
#define NP 320     // padded N for W_pad rows (4 waves * 80)
#define PK 320     // padded K for projection MFMA (10 * 32)
#define LSTR 328   // LDS h-tile stride (bank-conflict dodge, 16B-aligned)

typedef __attribute__((ext_vector_type(8))) short short8;
typedef __attribute__((ext_vector_type(4))) float f32x4;
typedef __hip_bfloat16 bf16;

// ---------------------------------------------------------------------------
// Prep: W_pad[320][608] bf16 (zero cols at 300..303, 604..607; zero rows >=300)
//       P_pad[16][320] bf16 (classes 0..4 valid)
// ---------------------------------------------------------------------------
__global__ __launch_bounds__(256) void prep_k(const float* __restrict__ Ww,
                                              const float* __restrict__ Pw,
                                              bf16* __restrict__ Wp,
                                              bf16* __restrict__ Pp) {
  int idx = blockIdx.x * 256 + threadIdx.x;
  if (idx < NP * KP) {
    int r = idx / KP, c = idx % KP;
    float v = 0.f;
    if (r < E_) {
      if (c < E_) v = Ww[r * 600 + c];
      else if (c >= HSTR && c < HSTR + E_) v = Ww[r * 600 + (c - 4)];
    }
    Wp[idx] = (bf16)v;
  }
  if (idx < 16 * PK) {
    int r = idx / PK, c = idx % PK;
    float v = (r < C_ && c < E_) ? Pw[r * E_ + c] : 0.f;
    Pp[idx] = (bf16)v;
  }
}

// ---------------------------------------------------------------------------
// Leaves: h0 = relu(emb[word]) stored bf16 stride 304, + fused projection
// (f32 weights, wave shuffle-reduce). One wave per row.
// ---------------------------------------------------------------------------
__global__ __launch_bounds__(256) void gather_proj_k(
    const int* __restrict__ wid, const float* __restrict__ emb,
    const float* __restrict__ Pw, const float* __restrict__ Pb,
    bf16* __restrict__ h0, float* __restrict__ out) {
  int w = (blockIdx.x * 256 + threadIdx.x) >> 6;
  int lane = threadIdx.x & 63;
  if (w >= B_ * L_) return;
  int word = wid[w];
  const float* src = emb + (size_t)word * E_;
  bf16* dst = h0 + (size_t)w * HSTR;
  float acc[C_] = {0.f, 0.f, 0.f, 0.f, 0.f};
#pragma unroll
  for (int i = 0; i < 5; i++) {
    int e = lane + 64 * i;
    if (e < E_) {
      float v = fmaxf(src[e], 0.f);
      dst[e] = (bf16)v;
#pragma unroll
      for (int c = 0; c < C_; c++) acc[c] += v * Pw[c * E_ + e];
    } else if (e < HSTR) {
      dst[e] = (bf16)0.f;
    }
  }
#pragma unroll
  for (int c = 0; c < C_; c++)
#pragma unroll
    for (int s = 32; s; s >>= 1) acc[c] += __shfl_down(acc[c], s, 64);
  if (lane == 0) {
    float* o = out + ((size_t)(w >> 10) * NODES + (w & 1023)) * C_;
#pragma unroll
    for (int c = 0; c < C_; c++) o[c] = acc[c] + Pb[c];
  }
}

// ---------------------------------------------------------------------------
// Combine level: out64 rows/block, 4 waves; wave w owns cols [80w, 80w+80)
// (5 n-tiles) x all 64 rows (4 row-tiles). A = h_in flat [m*608 + k].
// Fused projection via MFMA against P_pad after LDS round-trip.
// ---------------------------------------------------------------------------
__global__ __launch_bounds__(256) void combine_mfma_k(
    const bf16* __restrict__ h_in, const bf16* __restrict__ Wp,
    const float* __restrict__ Wb, const bf16* __restrict__ Pp,
    const float* __restrict__ Pb, bf16* __restrict__ h_out,
    float* __restrict__ out, int node_off, int nshift, int last) {
  __shared__ bf16 hs[64][LSTR];
  int tid = threadIdx.x;
  int w = tid >> 6;
  int l = tid & 63;
  int q = l & 15;
  int half = l >> 4;
  size_t m0 = (size_t)blockIdx.x * 64;

  f32x4 acc[4][5];
#pragma unroll
  for (int rt = 0; rt < 4; rt++)
#pragma unroll
    for (int nt = 0; nt < 5; nt++) acc[rt][nt] = (f32x4){0.f, 0.f, 0.f, 0.f};

#pragma unroll 2
  for (int ks = 0; ks < 19; ks++) {
    int k0 = ks * 32 + half * 8;
    short8 a[4], b[5];
#pragma unroll
    for (int rt = 0; rt < 4; rt++)
      a[rt] = *(const short8*)(h_in + (m0 + rt * 16 + q) * KP + k0);
#pragma unroll
    for (int nt = 0; nt < 5; nt++)
      b[nt] = *(const short8*)(Wp + (size_t)(w * 80 + nt * 16 + q) * KP + k0);
#pragma unroll
    for (int rt = 0; rt < 4; rt++)
#pragma unroll
      for (int nt = 0; nt < 5; nt++)
        acc[rt][nt] = __builtin_amdgcn_mfma_f32_16x16x32_bf16(
            a[rt], b[nt], acc[rt][nt], 0, 0, 0);
  }

  // epilogue: bias + relu, stash to LDS (and h_out for next level)
  float wb[5];
#pragma unroll
  for (int nt = 0; nt < 5; nt++) {
    int n = w * 80 + nt * 16 + q;
    wb[nt] = (n < E_) ? Wb[n] : 0.f;
  }
#pragma unroll
  for (int rt = 0; rt < 4; rt++) {
#pragma unroll
    for (int nt = 0; nt < 5; nt++) {
      int n = w * 80 + nt * 16 + q;
#pragma unroll
      for (int j = 0; j < 4; j++) {
        int rl = rt * 16 + half * 4 + j;
        float v = fmaxf(acc[rt][nt][j] + wb[nt], 0.f);
        if (n >= E_) v = 0.f;
        bf16 bv = (bf16)v;
        hs[rl][n] = bv;
        if (!last && n < HSTR) h_out[(m0 + rl) * HSTR + n] = bv;
      }
    }
  }
  __syncthreads();

  // projection: wave w handles rows [16w,16w+16); 10 MFMAs over K=320
  f32x4 pacc = (f32x4){0.f, 0.f, 0.f, 0.f};
#pragma unroll
  for (int ks = 0; ks < 10; ks++) {
    short8 a = *(const short8*)(&hs[16 * w + q][ks * 32 + half * 8]);
    short8 b = *(const short8*)(Pp + (size_t)q * PK + ks * 32 + half * 8);
    pacc = __builtin_amdgcn_mfma_f32_16x16x32_bf16(a, b, pacc, 0, 0, 0);
  }
  if (q < C_) {
    float pb = Pb[q];
#pragma unroll
    for (int j = 0; j < 4; j++) {
      size_t m = m0 + w * 16 + half * 4 + j;
      size_t b_ = m >> nshift;
      size_t n = m & (((size_t)1 << nshift) - 1);
      out[((size_t)b_ * NODES + node_off + n) * C_ + q] = pacc[j] + pb;
    }
  }
}

// ---------------------------------------------------------------------------
extern "C" void kernel_launch(void* const* d_in, const int* in_sizes, int n_in,
                              void* d_out, int out_size, void* d_ws,
                              size_t ws_size, hipStream_t stream) {
  const int* wid = (const int*)d_in[0];
  const float* emb = (const float*)d_in[1];
  const float* Ww = (const float*)d_in[2];
  const float* Wb = (const float*)d_in[3];
  const float* Pw = (const float*)d_in[4];
  const float* Pb = (const float*)d_in[5];
  float* out = (float*)d_out;

  bf16* hA = (bf16*)d_ws;
  size_t hA_elems = (size_t)B_ * L_ * HSTR;        // 39,845,888
  bf16* hB = hA + hA_elems;
  size_t hB_elems = (size_t)B_ * (L_ / 2) * HSTR;  // 19,922,944
  bf16* Wp = hB + hB_elems;
  bf16* Pp = Wp + (size_t)NP * KP;

  prep_k<<<(NP * KP + 255) / 256, 256, 0, stream>>>(Ww, Pw, Wp, Pp);
  gather_proj_k<<<(B_ * L_) / 4, 256, 0, stream>>>(wid, emb, Pw, Pb, hA, out);

  bf16* cur = hA;
  int node_off = L_;
  for (int lev = 1; lev <= D_; lev++) {
    int n_half = L_ >> lev;
    int M = B_ * n_half;
    bf16* nxt = (lev & 1) ? hB : hA;
    combine_mfma_k<<<M / 64, 256, 0, stream>>>(cur, Wp, Wb, Pp, Pb, nxt, out,
                                               node_off, D_ - lev,
                                               lev == D_ ? 1 : 0);
    node_off += n_half;
    cur = nxt;
  }
}

// Round 3
// 212.280 us; speedup vs baseline: 6.2188x; 1.3872x over previous
//
#include <hip/hip_runtime.h>
#include <hip/hip_bf16.h>

#define B_ 128
#define D_ 10
#define L_ 1024
#define E_ 300
#define C_ 5
#define NODES 2047
#define HSTR 304   // h row stride (300 + 4 zero pad)
#define KP 608     // pair-view K (= 2*HSTR) = 19*32
#define NP 320     // padded N (20 n-tiles of 16)
#define PK 320     // padded K for projection MFMA (10*32)
#define LSTR 328   // LDS output-tile stride
#define ASTR 616   // LDS staged-A stride (pair row, 608 + 8 pad)

typedef __attribute__((ext_vector_type(8))) short short8;
typedef __attribute__((ext_vector_type(4))) float f32x4;
typedef __hip_bfloat16 bf16;

__device__ __forceinline__ short f2bs(float v) {
  bf16 b = (bf16)v;
  return *reinterpret_cast<short*>(&b);
}

__device__ __forceinline__ short8 pack_relu(f32x4 v0, f32x4 v1) {
  short8 s;
#pragma unroll
  for (int j = 0; j < 4; j++) s[j] = f2bs(fmaxf(v0[j], 0.f));
#pragma unroll
  for (int j = 0; j < 4; j++) s[4 + j] = f2bs(fmaxf(v1[j], 0.f));
  return s;
}

// ---------------------------------------------------------------------------
// Prep: W_pad[320][608], P_pad[16][320], P_pair[2][16][608] (bf16, zero-padded)
// ---------------------------------------------------------------------------
__global__ __launch_bounds__(256) void prep_k(const float* __restrict__ Ww,
                                              const float* __restrict__ Pw,
                                              bf16* __restrict__ Wp,
                                              bf16* __restrict__ Pp,
                                              bf16* __restrict__ Pq) {
  int idx = blockIdx.x * 256 + threadIdx.x;
  if (idx < NP * KP) {
    int r = idx / KP, c = idx % KP;
    float v = 0.f;
    if (r < E_) {
      if (c < E_) v = Ww[r * 600 + c];
      else if (c >= HSTR && c < HSTR + E_) v = Ww[r * 600 + (c - 4)];
    }
    Wp[idx] = (bf16)v;
  }
  if (idx < 16 * PK) {
    int r = idx / PK, c = idx % PK;
    float v = (r < C_ && c < E_) ? Pw[r * E_ + c] : 0.f;
    Pp[idx] = (bf16)v;
  }
  if (idx < 2 * 16 * KP) {
    int p = idx / (16 * KP);
    int rem = idx % (16 * KP);
    int r = rem / KP, c = rem % KP;
    int e = c - p * HSTR;
    float v = (r < C_ && e >= 0 && e < E_) ? Pw[r * E_ + e] : 0.f;
    Pq[idx] = (bf16)v;
  }
}

// ---------------------------------------------------------------------------
// Fused: gather+relu (leaves) -> LDS, combine level 1, leaf proj, L1 proj.
// BM = 32 pair rows (= 64 leaf rows) per block, 4 waves.
// Wave w: combine cols [80w, 80w+80); leaf-proj parity p=w>>1, rt=w&1.
// ---------------------------------------------------------------------------
__global__ __launch_bounds__(256) void fused_l1_k(
    const int* __restrict__ wid, const float* __restrict__ emb,
    const bf16* __restrict__ Wp, const float* __restrict__ Wb,
    const bf16* __restrict__ Pq, const bf16* __restrict__ Pp,
    const float* __restrict__ Pb, bf16* __restrict__ h1,
    float* __restrict__ out) {
  __shared__ short hsA[32][ASTR];
  int tid = threadIdx.x;
  int m0 = blockIdx.x * 32;

  // stage: 32 pair rows x 608 (= 64 leaf rows), relu+bf16
  for (int i = tid; i < 32 * 76; i += 256) {
    int r = i / 76, c = i % 76;
    int par = c >= 38;
    int e0 = (c - 38 * par) * 8;
    int word = wid[2 * (m0 + r) + par];
    const float* src = emb + (size_t)word * E_ + e0;
    f32x4 v0 = *(const f32x4*)src;
    f32x4 v1;
    if (e0 == 296) v1 = (f32x4){0.f, 0.f, 0.f, 0.f};
    else v1 = *(const f32x4*)(src + 4);
    *(short8*)&hsA[r][c * 8] = pack_relu(v0, v1);
  }
  __syncthreads();

  int w = tid >> 6, l = tid & 63, q = l & 15, half = l >> 4;
  int p = w >> 1, rtl = w & 1;

  f32x4 acc[2][5];
#pragma unroll
  for (int rt = 0; rt < 2; rt++)
#pragma unroll
    for (int nt = 0; nt < 5; nt++) acc[rt][nt] = (f32x4){0.f, 0.f, 0.f, 0.f};
  f32x4 pacc = (f32x4){0.f, 0.f, 0.f, 0.f};

  for (int ks = 0; ks < 19; ks++) {
    int k0 = ks * 32 + half * 8;
    short8 a0 = *(const short8*)&hsA[q][k0];
    short8 a1 = *(const short8*)&hsA[16 + q][k0];
    // leaf projection chain (parity p, row tile rtl)
    short8 pf = *(const short8*)(Pq + ((size_t)p * 16 + q) * KP + k0);
    short8 al = rtl ? a1 : a0;
    pacc = __builtin_amdgcn_mfma_f32_16x16x32_bf16(al, pf, pacc, 0, 0, 0);
#pragma unroll
    for (int nt = 0; nt < 5; nt++) {
      short8 bfr =
          *(const short8*)(Wp + ((size_t)w * 80 + nt * 16 + q) * KP + k0);
      acc[0][nt] =
          __builtin_amdgcn_mfma_f32_16x16x32_bf16(a0, bfr, acc[0][nt], 0, 0, 0);
      acc[1][nt] =
          __builtin_amdgcn_mfma_f32_16x16x32_bf16(a1, bfr, acc[1][nt], 0, 0, 0);
    }
  }
  __syncthreads();  // all LDS A reads done; reuse LDS as output tile

  bf16(*hsO)[LSTR] = (bf16(*)[LSTR]) & hsA[0][0];
#pragma unroll
  for (int nt = 0; nt < 5; nt++) {
    int n = w * 80 + nt * 16 + q;
    float wb = (n < E_) ? Wb[n] : 0.f;
#pragma unroll
    for (int rt = 0; rt < 2; rt++)
#pragma unroll
      for (int j = 0; j < 4; j++) {
        int r = rt * 16 + half * 4 + j;
        hsO[r][n] = (bf16)fmaxf(acc[rt][nt][j] + wb, 0.f);
      }
  }
  // leaf logit stores
  if (q < C_) {
    float pb = Pb[q];
#pragma unroll
    for (int j = 0; j < 4; j++) {
      int mrow = m0 + rtl * 16 + half * 4 + j;
      int leaf = 2 * mrow + p;
      out[((size_t)(leaf >> 10) * NODES + (leaf & 1023)) * C_ + q] =
          pacc[j] + pb;
    }
  }
  __syncthreads();

  // cooperative h1 store (vector)
  for (int i = tid; i < 32 * 38; i += 256) {
    int r = i / 38, c = i % 38;
    *(short8*)(h1 + (size_t)(m0 + r) * HSTR + c * 8) =
        *(const short8*)&hsO[r][c * 8];
  }
  // L1 projection: waves 0,1 handle 16 rows each
  if (w < 2) {
    f32x4 pc = (f32x4){0.f, 0.f, 0.f, 0.f};
#pragma unroll
    for (int ks = 0; ks < 10; ks++) {
      int k0 = ks * 32 + half * 8;
      short8 a = *(const short8*)&hsO[w * 16 + q][k0];
      short8 bfr = *(const short8*)(Pp + (size_t)q * PK + k0);
      pc = __builtin_amdgcn_mfma_f32_16x16x32_bf16(a, bfr, pc, 0, 0, 0);
    }
    if (q < C_) {
      float pb = Pb[q];
#pragma unroll
      for (int j = 0; j < 4; j++) {
        int m = m0 + w * 16 + half * 4 + j;
        out[((size_t)(m >> 9) * NODES + 1024 + (m & 511)) * C_ + q] =
            pc[j] + pb;
      }
    }
  }
}

// ---------------------------------------------------------------------------
// Combine levels 2..5 (BM=64, 4 waves; A fragments from global h_in).
// ---------------------------------------------------------------------------
__global__ __launch_bounds__(256) void combine_mfma_k(
    const bf16* __restrict__ h_in, const bf16* __restrict__ Wp,
    const float* __restrict__ Wb, const bf16* __restrict__ Pp,
    const float* __restrict__ Pb, bf16* __restrict__ h_out,
    float* __restrict__ out, int node_off, int nshift) {
  __shared__ bf16 hs[64][LSTR];
  int tid = threadIdx.x;
  int w = tid >> 6;
  int l = tid & 63;
  int q = l & 15;
  int half = l >> 4;
  size_t m0 = (size_t)blockIdx.x * 64;

  f32x4 acc[4][5];
#pragma unroll
  for (int rt = 0; rt < 4; rt++)
#pragma unroll
    for (int nt = 0; nt < 5; nt++) acc[rt][nt] = (f32x4){0.f, 0.f, 0.f, 0.f};

#pragma unroll 2
  for (int ks = 0; ks < 19; ks++) {
    int k0 = ks * 32 + half * 8;
    short8 a[4], b[5];
#pragma unroll
    for (int rt = 0; rt < 4; rt++)
      a[rt] = *(const short8*)(h_in + (m0 + rt * 16 + q) * KP + k0);
#pragma unroll
    for (int nt = 0; nt < 5; nt++)
      b[nt] = *(const short8*)(Wp + (size_t)(w * 80 + nt * 16 + q) * KP + k0);
#pragma unroll
    for (int rt = 0; rt < 4; rt++)
#pragma unroll
      for (int nt = 0; nt < 5; nt++)
        acc[rt][nt] = __builtin_amdgcn_mfma_f32_16x16x32_bf16(
            a[rt], b[nt], acc[rt][nt], 0, 0, 0);
  }

  // epilogue: bias + relu into LDS
  float wb[5];
#pragma unroll
  for (int nt = 0; nt < 5; nt++) {
    int n = w * 80 + nt * 16 + q;
    wb[nt] = (n < E_) ? Wb[n] : 0.f;
  }
#pragma unroll
  for (int rt = 0; rt < 4; rt++)
#pragma unroll
    for (int nt = 0; nt < 5; nt++) {
      int n = w * 80 + nt * 16 + q;
#pragma unroll
      for (int j = 0; j < 4; j++) {
        int rl = rt * 16 + half * 4 + j;
        hs[rl][n] = (bf16)fmaxf(acc[rt][nt][j] + wb[nt], 0.f);
      }
    }
  __syncthreads();

  // cooperative vector store of h_out
  for (int i = tid; i < 64 * 38; i += 256) {
    int r = i / 38, c = i % 38;
    *(short8*)(h_out + (m0 + r) * HSTR + c * 8) = *(const short8*)&hs[r][c * 8];
  }

  // projection: wave w rows [16w, 16w+16)
  f32x4 pacc = (f32x4){0.f, 0.f, 0.f, 0.f};
#pragma unroll
  for (int ks = 0; ks < 10; ks++) {
    short8 a = *(const short8*)(&hs[16 * w + q][ks * 32 + half * 8]);
    short8 b = *(const short8*)(Pp + (size_t)q * PK + ks * 32 + half * 8);
    pacc = __builtin_amdgcn_mfma_f32_16x16x32_bf16(a, b, pacc, 0, 0, 0);
  }
  if (q < C_) {
    float pb = Pb[q];
#pragma unroll
    for (int j = 0; j < 4; j++) {
      size_t m = m0 + w * 16 + half * 4 + j;
      size_t b_ = m >> nshift;
      size_t n = m & (((size_t)1 << nshift) - 1);
      out[((size_t)b_ * NODES + node_off + n) * C_ + q] = pacc[j] + pb;
    }
  }
}

// ---------------------------------------------------------------------------
// Tail: levels 6..10 for one tree per block (input h5[b]: 32 rows).
// LDS ping-pong; garbage rows beyond valid M are confined (row-local MFMA)
// and masked at store time.
// ---------------------------------------------------------------------------
__global__ __launch_bounds__(256) void tail_k(
    const bf16* __restrict__ h5, const bf16* __restrict__ Wp,
    const float* __restrict__ Wb, const bf16* __restrict__ Pp,
    const float* __restrict__ Pb, float* __restrict__ out) {
  __shared__ bf16 bufs[2][32][LSTR];
  int tid = threadIdx.x, b = blockIdx.x;
  int w = tid >> 6, l = tid & 63, q = l & 15, half = l >> 4;

  for (int i = tid; i < 32 * 38; i += 256) {
    int r = i / 38, c = i % 38;
    *(short8*)&bufs[0][r][c * 8] =
        *(const short8*)(h5 + ((size_t)b * 32 + r) * HSTR + c * 8);
  }
  __syncthreads();

  int p = 0, off = 2016, Mo = 16;
  for (int lev = 0; lev < 5; lev++) {
    f32x4 acc[5];
#pragma unroll
    for (int t = 0; t < 5; t++) acc[t] = (f32x4){0.f, 0.f, 0.f, 0.f};
    for (int ks = 0; ks < 19; ks++) {
      int k0 = ks * 32 + half * 8;
      int sel = k0 >= HSTR;
      int e0 = k0 - (sel ? HSTR : 0);
      short8 a = *(const short8*)&bufs[p][2 * q + sel][e0];
#pragma unroll
      for (int t = 0; t < 5; t++) {
        int nt = w + 4 * t;
        short8 bfr = *(const short8*)(Wp + ((size_t)nt * 16 + q) * KP + k0);
        acc[t] = __builtin_amdgcn_mfma_f32_16x16x32_bf16(a, bfr, acc[t], 0, 0, 0);
      }
    }
    __syncthreads();
#pragma unroll
    for (int t = 0; t < 5; t++) {
      int nt = w + 4 * t;
      int n = nt * 16 + q;
      float wb = (n < E_) ? Wb[n] : 0.f;
#pragma unroll
      for (int j = 0; j < 4; j++) {
        int r = half * 4 + j;
        bufs[p ^ 1][r][n] = (bf16)fmaxf(acc[t][j] + wb, 0.f);
      }
    }
    __syncthreads();
    if (w == 0) {
      f32x4 pc = (f32x4){0.f, 0.f, 0.f, 0.f};
#pragma unroll
      for (int ks = 0; ks < 10; ks++) {
        int k0 = ks * 32 + half * 8;
        short8 a = *(const short8*)&bufs[p ^ 1][q][k0];
        short8 bfr = *(const short8*)(Pp + (size_t)q * PK + k0);
        pc = __builtin_amdgcn_mfma_f32_16x16x32_bf16(a, bfr, pc, 0, 0, 0);
      }
      if (q < C_) {
        float pb = Pb[q];
#pragma unroll
        for (int j = 0; j < 4; j++) {
          int r = half * 4 + j;
          if (r < Mo)
            out[((size_t)b * NODES + off + r) * C_ + q] = pc[j] + pb;
        }
      }
    }
    p ^= 1;
    off += Mo;
    Mo >>= 1;
  }
}

// ---------------------------------------------------------------------------
extern "C" void kernel_launch(void* const* d_in, const int* in_sizes, int n_in,
                              void* d_out, int out_size, void* d_ws,
                              size_t ws_size, hipStream_t stream) {
  const int* wid = (const int*)d_in[0];
  const float* emb = (const float*)d_in[1];
  const float* Ww = (const float*)d_in[2];
  const float* Wb = (const float*)d_in[3];
  const float* Pw = (const float*)d_in[4];
  const float* Pb = (const float*)d_in[5];
  float* out = (float*)d_out;

  bf16* hA = (bf16*)d_ws;                          // h1, h3, h5 (19.9M elems)
  bf16* hB = hA + (size_t)B_ * 512 * HSTR;         // h2, h4     (9.96M elems)
  bf16* Wp = hB + (size_t)B_ * 256 * HSTR;
  bf16* Pp = Wp + (size_t)NP * KP;
  bf16* Pq = Pp + (size_t)16 * PK;

  prep_k<<<(NP * KP + 255) / 256, 256, 0, stream>>>(Ww, Pw, Wp, Pp, Pq);
  fused_l1_k<<<(B_ * 512) / 32, 256, 0, stream>>>(wid, emb, Wp, Wb, Pq, Pp, Pb,
                                                  hA, out);
  bf16* cur = hA;
  int node_off = 1536;
  for (int lev = 2; lev <= 5; lev++) {
    int n_half = L_ >> lev;
    int M = B_ * n_half;
    bf16* nxt = (lev & 1) ? hA : hB;
    combine_mfma_k<<<M / 64, 256, 0, stream>>>(cur, Wp, Wb, Pp, Pb, nxt, out,
                                               node_off, D_ - lev);
    node_off += n_half;
    cur = nxt;
  }
  tail_k<<<B_, 256, 0, stream>>>(cur, Wp, Wb, Pp, Pb, out);
}

// Round 4
// 211.441 us; speedup vs baseline: 6.2435x; 1.0040x over previous
//
#include <hip/hip_runtime.h>
#include <hip/hip_bf16.h>

#define B_ 128
#define D_ 10
#define L_ 1024
#define E_ 300
#define C_ 5
#define NODES 2047
#define HSTR 304   // h / T row stride (300 + 4 zero pad)
#define KP 608     // pair-view K (= 2*HSTR) = 19*32
#define NP 320     // padded N (20 n-tiles of 16)
#define PK 320     // padded K for projection MFMA (10*32)
#define LSTR 328   // LDS output-tile stride

typedef __attribute__((ext_vector_type(8))) short short8;
typedef __attribute__((ext_vector_type(4))) float f32x4;
typedef __hip_bfloat16 bf16;

__device__ __forceinline__ short f2bs(float v) {
  bf16 b = (bf16)v;
  return *reinterpret_cast<short*>(&b);
}

__device__ __forceinline__ short8 pack_relu(f32x4 v0, f32x4 v1) {
  short8 s;
#pragma unroll
  for (int j = 0; j < 4; j++) s[j] = f2bs(fmaxf(v0[j], 0.f));
#pragma unroll
  for (int j = 0; j < 4; j++) s[4 + j] = f2bs(fmaxf(v1[j], 0.f));
  return s;
}

// ---------------------------------------------------------------------------
// Prep: T[V][304] = bf16(relu(emb)), W_pad[320][608], P_pad[16][320],
//       P_pair[2][16][608]  (all bf16, zero-padded)
// ---------------------------------------------------------------------------
__global__ __launch_bounds__(256) void prep_k(
    const float* __restrict__ emb, const float* __restrict__ Ww,
    const float* __restrict__ Pw, bf16* __restrict__ T, bf16* __restrict__ Wp,
    bf16* __restrict__ Pp, bf16* __restrict__ Pq, int V) {
  int idx = blockIdx.x * 256 + threadIdx.x;
  int tchunks = V * 38;  // 38 short8 chunks per 304-elem row
  if (idx < tchunks) {
    int v = idx / 38, c = idx % 38;
    const float* src = emb + (size_t)v * E_ + c * 8;
    f32x4 v0 = *(const f32x4*)src;
    f32x4 v1;
    if (c == 37) v1 = (f32x4){0.f, 0.f, 0.f, 0.f};
    else v1 = *(const f32x4*)(src + 4);
    *(short8*)(T + (size_t)v * HSTR + c * 8) = pack_relu(v0, v1);
  }
  if (idx < NP * KP) {
    int r = idx / KP, c = idx % KP;
    float v = 0.f;
    if (r < E_) {
      if (c < E_) v = Ww[r * 600 + c];
      else if (c >= HSTR && c < HSTR + E_) v = Ww[r * 600 + (c - 4)];
    }
    Wp[idx] = (bf16)v;
  }
  if (idx < 16 * PK) {
    int r = idx / PK, c = idx % PK;
    float v = (r < C_ && c < E_) ? Pw[r * E_ + c] : 0.f;
    Pp[idx] = (bf16)v;
  }
  if (idx < 2 * 16 * KP) {
    int p = idx / (16 * KP);
    int rem = idx % (16 * KP);
    int r = rem / KP, c = rem % KP;
    int e = c - p * HSTR;
    float v = (r < C_ && e >= 0 && e < E_) ? Pw[r * E_ + e] : 0.f;
    Pq[idx] = (bf16)v;
  }
}

// ---------------------------------------------------------------------------
// Fused level 1: stage-free. Block = 64 pair rows, 4 waves.
// Wave w: combine cols [80w, 80w+80) x all 64 rows (4 row-tiles), reading
// A-fragments straight from T via word-id indirection. Leaf projection:
// wave w projects row-tile rt=w, both parities. Zero main-loop syncs.
// ---------------------------------------------------------------------------
__global__ __launch_bounds__(256) void fused_l1_k(
    const int* __restrict__ wid, const bf16* __restrict__ T,
    const bf16* __restrict__ Wp, const float* __restrict__ Wb,
    const bf16* __restrict__ Pq, const bf16* __restrict__ Pp,
    const float* __restrict__ Pb, bf16* __restrict__ h1,
    float* __restrict__ out) {
  __shared__ bf16 hs[64][LSTR];
  int tid = threadIdx.x;
  int w = tid >> 6, l = tid & 63, q = l & 15, half = l >> 4;
  int m0 = blockIdx.x * 64;

  // per-lane A row byte bases (u32 offsets into T, rows are 608 B)
  int off0[4], off1[4];
#pragma unroll
  for (int rt = 0; rt < 4; rt++) {
    int mrow = m0 + rt * 16 + q;
    off0[rt] = wid[2 * mrow] * HSTR;
    off1[rt] = wid[2 * mrow + 1] * HSTR;
  }
  // leaf-proj row (rt = w) bases
  int lm = m0 + w * 16 + q;
  int lb0 = wid[2 * lm] * HSTR;
  int lb1 = wid[2 * lm + 1] * HSTR;

  f32x4 acc[4][5];
#pragma unroll
  for (int rt = 0; rt < 4; rt++)
#pragma unroll
    for (int nt = 0; nt < 5; nt++) acc[rt][nt] = (f32x4){0.f, 0.f, 0.f, 0.f};
  f32x4 pacc[2];
  pacc[0] = pacc[1] = (f32x4){0.f, 0.f, 0.f, 0.f};

  for (int ks = 0; ks < 19; ks++) {
    int k0 = ks * 32 + half * 8;
    int sel = k0 >= HSTR;
    int e0 = sel ? k0 - HSTR : k0;
    short8 a[4];
#pragma unroll
    for (int rt = 0; rt < 4; rt++)
      a[rt] = *(const short8*)(T + (sel ? off1[rt] : off0[rt]) + e0);
    // leaf projection (extra load of row-tile w; L1-hit, avoids runtime idx)
    short8 al = *(const short8*)(T + (sel ? lb1 : lb0) + e0);
    short8 pq0 = *(const short8*)(Pq + (size_t)q * KP + k0);
    short8 pq1 = *(const short8*)(Pq + (size_t)(16 + q) * KP + k0);
    pacc[0] = __builtin_amdgcn_mfma_f32_16x16x32_bf16(al, pq0, pacc[0], 0, 0, 0);
    pacc[1] = __builtin_amdgcn_mfma_f32_16x16x32_bf16(al, pq1, pacc[1], 0, 0, 0);
#pragma unroll
    for (int nt = 0; nt < 5; nt++) {
      short8 b =
          *(const short8*)(Wp + (size_t)(w * 80 + nt * 16 + q) * KP + k0);
#pragma unroll
      for (int rt = 0; rt < 4; rt++)
        acc[rt][nt] = __builtin_amdgcn_mfma_f32_16x16x32_bf16(a[rt], b,
                                                              acc[rt][nt], 0,
                                                              0, 0);
    }
  }

  // epilogue: bias + relu into LDS
#pragma unroll
  for (int nt = 0; nt < 5; nt++) {
    int n = w * 80 + nt * 16 + q;
    float wb = (n < E_) ? Wb[n] : 0.f;
#pragma unroll
    for (int rt = 0; rt < 4; rt++)
#pragma unroll
      for (int j = 0; j < 4; j++) {
        int rl = rt * 16 + half * 4 + j;
        hs[rl][n] = (bf16)fmaxf(acc[rt][nt][j] + wb, 0.f);
      }
  }
  // leaf logit stores (register-resident, no LDS needed)
  if (q < C_) {
    float pb = Pb[q];
#pragma unroll
    for (int p = 0; p < 2; p++)
#pragma unroll
      for (int j = 0; j < 4; j++) {
        int leaf = 2 * (m0 + w * 16 + half * 4 + j) + p;
        out[((size_t)(leaf >> 10) * NODES + (leaf & 1023)) * C_ + q] =
            pacc[p][j] + pb;
      }
  }
  __syncthreads();

  // cooperative vector store of h1
  for (int i = tid; i < 64 * 38; i += 256) {
    int r = i / 38, c = i % 38;
    *(short8*)(h1 + (size_t)(m0 + r) * HSTR + c * 8) =
        *(const short8*)&hs[r][c * 8];
  }
  // L1 projection: wave w rows [16w, 16w+16)
  f32x4 pc = (f32x4){0.f, 0.f, 0.f, 0.f};
#pragma unroll
  for (int ks = 0; ks < 10; ks++) {
    int k0 = ks * 32 + half * 8;
    short8 a = *(const short8*)&hs[16 * w + q][k0];
    short8 b = *(const short8*)(Pp + (size_t)q * PK + k0);
    pc = __builtin_amdgcn_mfma_f32_16x16x32_bf16(a, b, pc, 0, 0, 0);
  }
  if (q < C_) {
    float pb = Pb[q];
#pragma unroll
    for (int j = 0; j < 4; j++) {
      int m = m0 + w * 16 + half * 4 + j;
      out[((size_t)(m >> 9) * NODES + 1024 + (m & 511)) * C_ + q] = pc[j] + pb;
    }
  }
}

// ---------------------------------------------------------------------------
// Combine levels 2..5 (BM=64 output rows, 4 waves; A from global h_in).
// ---------------------------------------------------------------------------
__global__ __launch_bounds__(256) void combine_mfma_k(
    const bf16* __restrict__ h_in, const bf16* __restrict__ Wp,
    const float* __restrict__ Wb, const bf16* __restrict__ Pp,
    const float* __restrict__ Pb, bf16* __restrict__ h_out,
    float* __restrict__ out, int node_off, int nshift) {
  __shared__ bf16 hs[64][LSTR];
  int tid = threadIdx.x;
  int w = tid >> 6;
  int l = tid & 63;
  int q = l & 15;
  int half = l >> 4;
  size_t m0 = (size_t)blockIdx.x * 64;

  f32x4 acc[4][5];
#pragma unroll
  for (int rt = 0; rt < 4; rt++)
#pragma unroll
    for (int nt = 0; nt < 5; nt++) acc[rt][nt] = (f32x4){0.f, 0.f, 0.f, 0.f};

#pragma unroll 2
  for (int ks = 0; ks < 19; ks++) {
    int k0 = ks * 32 + half * 8;
    short8 a[4], b[5];
#pragma unroll
    for (int rt = 0; rt < 4; rt++)
      a[rt] = *(const short8*)(h_in + (m0 + rt * 16 + q) * KP + k0);
#pragma unroll
    for (int nt = 0; nt < 5; nt++)
      b[nt] = *(const short8*)(Wp + (size_t)(w * 80 + nt * 16 + q) * KP + k0);
#pragma unroll
    for (int rt = 0; rt < 4; rt++)
#pragma unroll
      for (int nt = 0; nt < 5; nt++)
        acc[rt][nt] = __builtin_amdgcn_mfma_f32_16x16x32_bf16(
            a[rt], b[nt], acc[rt][nt], 0, 0, 0);
  }

  float wb[5];
#pragma unroll
  for (int nt = 0; nt < 5; nt++) {
    int n = w * 80 + nt * 16 + q;
    wb[nt] = (n < E_) ? Wb[n] : 0.f;
  }
#pragma unroll
  for (int rt = 0; rt < 4; rt++)
#pragma unroll
    for (int nt = 0; nt < 5; nt++) {
      int n = w * 80 + nt * 16 + q;
#pragma unroll
      for (int j = 0; j < 4; j++) {
        int rl = rt * 16 + half * 4 + j;
        hs[rl][n] = (bf16)fmaxf(acc[rt][nt][j] + wb[nt], 0.f);
      }
    }
  __syncthreads();

  for (int i = tid; i < 64 * 38; i += 256) {
    int r = i / 38, c = i % 38;
    *(short8*)(h_out + (m0 + r) * HSTR + c * 8) = *(const short8*)&hs[r][c * 8];
  }

  f32x4 pacc = (f32x4){0.f, 0.f, 0.f, 0.f};
#pragma unroll
  for (int ks = 0; ks < 10; ks++) {
    short8 a = *(const short8*)(&hs[16 * w + q][ks * 32 + half * 8]);
    short8 b = *(const short8*)(Pp + (size_t)q * PK + ks * 32 + half * 8);
    pacc = __builtin_amdgcn_mfma_f32_16x16x32_bf16(a, b, pacc, 0, 0, 0);
  }
  if (q < C_) {
    float pb = Pb[q];
#pragma unroll
    for (int j = 0; j < 4; j++) {
      size_t m = m0 + w * 16 + half * 4 + j;
      size_t b_ = m >> nshift;
      size_t n = m & (((size_t)1 << nshift) - 1);
      out[((size_t)b_ * NODES + node_off + n) * C_ + q] = pacc[j] + pb;
    }
  }
}

// ---------------------------------------------------------------------------
// Tail: levels 6..10, one tree per block (input h5[b]: 32 rows).
// ---------------------------------------------------------------------------
__global__ __launch_bounds__(256) void tail_k(
    const bf16* __restrict__ h5, const bf16* __restrict__ Wp,
    const float* __restrict__ Wb, const bf16* __restrict__ Pp,
    const float* __restrict__ Pb, float* __restrict__ out) {
  __shared__ bf16 bufs[2][32][LSTR];
  int tid = threadIdx.x, b = blockIdx.x;
  int w = tid >> 6, l = tid & 63, q = l & 15, half = l >> 4;

  for (int i = tid; i < 32 * 38; i += 256) {
    int r = i / 38, c = i % 38;
    *(short8*)&bufs[0][r][c * 8] =
        *(const short8*)(h5 + ((size_t)b * 32 + r) * HSTR + c * 8);
  }
  __syncthreads();

  int p = 0, off = 2016, Mo = 16;
  for (int lev = 0; lev < 5; lev++) {
    f32x4 acc[5];
#pragma unroll
    for (int t = 0; t < 5; t++) acc[t] = (f32x4){0.f, 0.f, 0.f, 0.f};
    for (int ks = 0; ks < 19; ks++) {
      int k0 = ks * 32 + half * 8;
      int sel = k0 >= HSTR;
      int e0 = k0 - (sel ? HSTR : 0);
      short8 a = *(const short8*)&bufs[p][2 * q + sel][e0];
#pragma unroll
      for (int t = 0; t < 5; t++) {
        int nt = w + 4 * t;
        short8 bfr = *(const short8*)(Wp + ((size_t)nt * 16 + q) * KP + k0);
        acc[t] =
            __builtin_amdgcn_mfma_f32_16x16x32_bf16(a, bfr, acc[t], 0, 0, 0);
      }
    }
    __syncthreads();
#pragma unroll
    for (int t = 0; t < 5; t++) {
      int nt = w + 4 * t;
      int n = nt * 16 + q;
      float wb = (n < E_) ? Wb[n] : 0.f;
#pragma unroll
      for (int j = 0; j < 4; j++) {
        int r = half * 4 + j;
        bufs[p ^ 1][r][n] = (bf16)fmaxf(acc[t][j] + wb, 0.f);
      }
    }
    __syncthreads();
    if (w == 0) {
      f32x4 pc = (f32x4){0.f, 0.f, 0.f, 0.f};
#pragma unroll
      for (int ks = 0; ks < 10; ks++) {
        int k0 = ks * 32 + half * 8;
        short8 a = *(const short8*)&bufs[p ^ 1][q][k0];
        short8 bfr = *(const short8*)(Pp + (size_t)q * PK + k0);
        pc = __builtin_amdgcn_mfma_f32_16x16x32_bf16(a, bfr, pc, 0, 0, 0);
      }
      if (q < C_) {
        float pb = Pb[q];
#pragma unroll
        for (int j = 0; j < 4; j++) {
          int r = half * 4 + j;
          if (r < Mo) out[((size_t)b * NODES + off + r) * C_ + q] = pc[j] + pb;
        }
      }
    }
    p ^= 1;
    off += Mo;
    Mo >>= 1;
  }
}

// ---------------------------------------------------------------------------
extern "C" void kernel_launch(void* const* d_in, const int* in_sizes, int n_in,
                              void* d_out, int out_size, void* d_ws,
                              size_t ws_size, hipStream_t stream) {
  const int* wid = (const int*)d_in[0];
  const float* emb = (const float*)d_in[1];
  const float* Ww = (const float*)d_in[2];
  const float* Wb = (const float*)d_in[3];
  const float* Pw = (const float*)d_in[4];
  const float* Pb = (const float*)d_in[5];
  float* out = (float*)d_out;
  int V = in_sizes[1] / E_;  // 50000

  bf16* hA = (bf16*)d_ws;                    // h1, h3, h5
  bf16* hB = hA + (size_t)B_ * 512 * HSTR;   // h2, h4
  bf16* Wp = hB + (size_t)B_ * 256 * HSTR;
  bf16* Pp = Wp + (size_t)NP * KP;
  bf16* Pq = Pp + (size_t)16 * PK;
  bf16* T = Pq + (size_t)2 * 16 * KP;        // V * 304

  int tchunks = V * 38;
  prep_k<<<(tchunks + 255) / 256, 256, 0, stream>>>(emb, Ww, Pw, T, Wp, Pp, Pq,
                                                    V);
  fused_l1_k<<<(B_ * 512) / 64, 256, 0, stream>>>(wid, T, Wp, Wb, Pq, Pp, Pb,
                                                  hA, out);
  bf16* cur = hA;
  int node_off = 1536;
  for (int lev = 2; lev <= 5; lev++) {
    int n_half = L_ >> lev;
    int M = B_ * n_half;
    bf16* nxt = (lev & 1) ? hA : hB;
    combine_mfma_k<<<M / 64, 256, 0, stream>>>(cur, Wp, Wb, Pp, Pb, nxt, out,
                                               node_off, D_ - lev);
    node_off += n_half;
    cur = nxt;
  }
  tail_k<<<B_, 256, 0, stream>>>(cur, Wp, Wb, Pp, Pb, out);
}